// Round 8
// baseline (1606.000 us; speedup 1.0000x reference)
//
#include <hip/hip_runtime.h>
#include <hip/hip_bf16.h>

// Problem constants
#define BB 16
#define NN 8192
#define SS 1024
#define GG 32
// sortable(1.0f) = 0x3F800000 ^ 0x80000000
#define SORT_R2 0xBF800000u

typedef float v2f __attribute__((ext_vector_type(2)));

__device__ __forceinline__ unsigned sortable(float f) {
    unsigned u = __float_as_uint(f);
    return u ^ ((unsigned)(((int)u) >> 31) | 0x80000000u);
}

// f32 max-combine with a DPP-permuted copy (2 slots: v_mov_dpp + v_max_f32).
// row_shr:n = 0x110|n, row_bcast15 = 0x142, row_bcast31 = 0x143.
template <int CTRL, int RM>
__device__ __forceinline__ float dpp_maxf(float v) {
    int i = __float_as_int(v);
    int p = __builtin_amdgcn_update_dpp(i, i, CTRL, RM, 0xF, false);
    return fmaxf(v, __int_as_float(p));
}

// u32 min-combine with a DPP-permuted copy (2 slots).
template <int CTRL, int RM>
__device__ __forceinline__ unsigned dpp_minu(unsigned v) {
    int p = __builtin_amdgcn_update_dpp((int)v, (int)v, CTRL, RM, 0xF, false);
    return min(v, (unsigned)p);
}

__device__ __forceinline__ unsigned wave_minu(unsigned v) {
    v = dpp_minu<0x111, 0xF>(v);
    v = dpp_minu<0x112, 0xF>(v);
    v = dpp_minu<0x114, 0xF>(v);
    v = dpp_minu<0x118, 0xF>(v);
    v = dpp_minu<0x142, 0xA>(v);
    v = dpp_minu<0x143, 0xC>(v);
    return (unsigned)__builtin_amdgcn_readlane((int)v, 63);
}

__device__ __forceinline__ float fmax3(float a, float b, float c) {
    return fmaxf(fmaxf(a, b), c);   // fuses to v_max3_f32
}

// ---------------------------------------------------------------------------
// Kernel 1: pack pts4[b][n] = {x, y, z, (x*x+y*y)+z*z}  (rn ops, no contraction)
// ---------------------------------------------------------------------------
__global__ __launch_bounds__(256) void k_pts(const float* __restrict__ coor,
                                             float4* __restrict__ pts4) {
    int i = blockIdx.x * 256 + threadIdx.x;   // 0 .. B*N-1
    int b = i >> 13, n = i & (NN - 1);
    const float* cb = coor + (long)b * 3 * NN;
    float x = cb[n], y = cb[NN + n], z = cb[2 * NN + n];
    float pn = __fadd_rn(__fadd_rn(__fmul_rn(x, x), __fmul_rn(y, y)), __fmul_rn(z, z));
    pts4[i] = make_float4(x, y, z, pn);
}

// ---------------------------------------------------------------------------
// Kernel 2: transpose fea (B,64,N) -> feaT (B,N,64)
// ---------------------------------------------------------------------------
__global__ __launch_bounds__(256) void k_tr(const float* __restrict__ fea,
                                            float* __restrict__ feaT) {
    __shared__ float tile[64][65];
    int b = blockIdx.y, n0 = blockIdx.x * 64;
    int t = threadIdx.x;
    int nl = t & 63, cb = t >> 6;
#pragma unroll
    for (int i = 0; i < 16; i++) {
        int c = cb * 16 + i;
        tile[nl][c] = fea[((long)b * 64 + c) * NN + n0 + nl];
    }
    __syncthreads();
    int cl = t & 63, nb = t >> 6;
#pragma unroll
    for (int i = 0; i < 16; i++) {
        int n = nb * 16 + i;
        feaT[((long)b * NN + n0 + n) * 64 + cl] = tile[n][cl];
    }
}

// ---------------------------------------------------------------------------
// Kernel 3: farthest point sampling. One block per batch.
// v8: v5's two-barrier value-first scheme at 1024 threads (4 waves/SIMD).
// R6/R7 showed the limiter is per-wave serial issue + unoverlapped LDS/
// barrier latency, NOT barrier population: more resident waves per SIMD =
// more overlap. 8 points/thread (4 v2f pairs). Distance math contract(off)
// packed v2f: bit-exact rn ops; tie semantics exact (atomicMin on flat idx).
// ---------------------------------------------------------------------------
__global__ __launch_bounds__(1024, 1) void k_fps(const float4* __restrict__ pts4,
                                                 float4* __restrict__ qpts,
                                                 float* __restrict__ out) {
#pragma clang fp contract(off)
    __shared__ float xs[NN], ys[NN], zs[NN];
    __shared__ int scur[SS];
    __shared__ __align__(16) float redv[2][16];
    __shared__ int sidx[2];
    int b = blockIdx.x;
    int t = threadIdx.x;
    const float4* P = pts4 + (long)b * NN;

    // pair j, half h -> point p = t + (2j+h)*1024
    v2f px[4], py[4], pz[4], dist[4];
#pragma unroll
    for (int j = 0; j < 4; j++) {
        int p0 = t + (2 * j) * 1024;
        int p1 = t + (2 * j + 1) * 1024;
        float4 a = P[p0];
        float4 c = P[p1];
        px[j] = v2f{a.x, c.x};
        py[j] = v2f{a.y, c.y};
        pz[j] = v2f{a.z, c.z};
        dist[j] = v2f{1e10f, 1e10f};
        xs[p0] = a.x; ys[p0] = a.y; zs[p0] = a.z;
        xs[p1] = c.x; ys[p1] = c.y; zs[p1] = c.z;
    }
    if (t == 0) { sidx[0] = 0x7FFFFFFF; sidx[1] = 0x7FFFFFFF; }
    __syncthreads();

    int cur = 0;
    for (int s = 0; s < SS; s++) {
        int par = s & 1;
        float cx = xs[cur], cy = ys[cur], cz = zs[cur];
        if (t == 0) scur[s] = cur;
        v2f cx2 = v2f{cx, cx}, cy2 = v2f{cy, cy}, cz2 = v2f{cz, cz};
#pragma unroll
        for (int j = 0; j < 4; j++) {
            v2f dx = px[j] - cx2;
            v2f dy = py[j] - cy2;
            v2f dz = pz[j] - cz2;
            v2f xx = dx * dx;
            v2f yy = dy * dy;
            v2f zz = dz * dz;
            v2f sm = xx + yy;
            v2f d = sm + zz;
            dist[j] = __builtin_elementwise_min(dist[j], d);
        }
        // value-only per-thread max (3 pk-max + 1 scalar)
        v2f ma = __builtin_elementwise_max(dist[0], dist[1]);
        v2f mb = __builtin_elementwise_max(dist[2], dist[3]);
        v2f mm = __builtin_elementwise_max(ma, mb);
        float bv = fmaxf(mm.x, mm.y);
        // 64-lane DPP f32 max; full-wave max lands in lane 63
        float wv = bv;
        wv = dpp_maxf<0x111, 0xF>(wv);   // row_shr:1
        wv = dpp_maxf<0x112, 0xF>(wv);   // row_shr:2
        wv = dpp_maxf<0x114, 0xF>(wv);   // row_shr:4
        wv = dpp_maxf<0x118, 0xF>(wv);   // row_shr:8
        wv = dpp_maxf<0x142, 0xA>(wv);   // row_bcast:15 (rows 1,3)
        wv = dpp_maxf<0x143, 0xC>(wv);   // row_bcast:31 (rows 2,3)
        if ((t & 63) == 63) redv[par][t >> 6] = wv;
        __syncthreads();                 // barrier 1
        const float4* rv = (const float4*)redv[par];
        float4 r0 = rv[0], r1 = rv[1], r2 = rv[2], r3 = rv[3];
        float g0 = fmaxf(fmax3(r0.x, r0.y, r0.z),
                         fmax3(r0.w, fmax3(r1.x, r1.y, r1.z), r1.w));
        float g1 = fmaxf(fmax3(r2.x, r2.y, r2.z),
                         fmax3(r2.w, fmax3(r3.x, r3.y, r3.z), r3.w));
        float gmax = fmaxf(g0, g1);
        // reset the OTHER sidx slot (used at s+1); barrier 2 separates it
        // from s+1's atomics.
        if (t == 0) sidx[1 - par] = 0x7FFFFFFF;
        if (bv == gmax) {
            // block-rare path (usually 1 thread): lowest matching ord
            int jj = 8;
#pragma unroll
            for (int j = 3; j >= 0; j--) {
                jj = (dist[j].y == gmax) ? (2 * j + 1) : jj;
                jj = (dist[j].x == gmax) ? (2 * j) : jj;
            }
            atomicMin(&sidx[par], t + jj * 1024);
        }
        __syncthreads();                 // barrier 2
        cur = sidx[par];
    }
    __syncthreads();

    // epilogue: one sample per thread
    {
        int s = t;
        int c = scur[s];
        float cx = xs[c], cy = ys[c], cz = zs[c];
        out[(long)b * 3 * SS + s]          = cx;
        out[(long)b * 3 * SS + SS + s]     = cy;
        out[(long)b * 3 * SS + 2 * SS + s] = cz;
        float qn = __fadd_rn(__fadd_rn(__fmul_rn(cx, cx), __fmul_rn(cy, cy)),
                             __fmul_rn(cz, cz));
        qpts[(long)b * SS + s] = make_float4(cx, cy, cz, qn);
    }
}

// ---------------------------------------------------------------------------
// Kernel 4: exact 32-NN per query, reference formula d = (qn - 2*dot) + pn;
// stable tie-break by index (matches lax.top_k); radius d > 1.0 -> nearest.
// v3: TWO waves per query (128 thr). dk LDS caps residency at 4 blocks/CU,
// so 2 waves/query doubles waves/CU (4->8) and halves the latency-bound
// initial scan (64 iters). Skew p+(p>>7): scan stride-1 and rescan
// stride-129 both conflict-free. Thread t owns column {p : p==t mod 128}
// (p monotone in j -> earliest-index ties exact). Cross-wave resolve
// compares (val,pos) explicitly; rescan fast path exact because column p
// is monotone in lane.
// ---------------------------------------------------------------------------
#define SKN(p) ((p) + ((p) >> 7))
__global__ __launch_bounds__(128) void k_knn(const float4* __restrict__ pts4,
                                             const float4* __restrict__ qpts,
                                             int* __restrict__ gidx) {
    __shared__ unsigned dk[NN + NN / 128];   // 8256
    __shared__ unsigned wvals[2];
    __shared__ int wposs[2];
    __shared__ unsigned colv;
    __shared__ int colp;
    int Q = blockIdx.x;                      // b*1024 + s
    int b = Q >> 10;
    int t = threadIdx.x;
    int w = t >> 6, l = t & 63;
    float4 q = qpts[Q];
    const float4* P = pts4 + (long)b * NN;

    unsigned bmin = 0xFFFFFFFFu;
    int bpos = 0;
#pragma unroll 4
    for (int j = 0; j < 64; j++) {
        int p = j * 128 + t;
        float4 v = P[p];
        float dot = __fadd_rn(__fadd_rn(__fmul_rn(q.x, v.x), __fmul_rn(q.y, v.y)),
                              __fmul_rn(q.z, v.z));
        float d = __fadd_rn(__fsub_rn(q.w, __fmul_rn(2.0f, dot)), v.w);
        unsigned u = sortable(d);
        dk[SKN(p)] = u;
        if (u < bmin) { bmin = u; bpos = p; }   // ascending p -> earliest on tie
    }
    __syncthreads();

    unsigned resv = 0;
    int resp = 0, pos0 = 0;
    for (int k = 0; k < GG; k++) {
        // per-wave (value, pos) candidate
        unsigned wmin = wave_minu(bmin);
        unsigned long long mask = __ballot(bmin == wmin);
        int wp;
        if (__builtin_popcountll(mask) == 1) {
            wp = __builtin_amdgcn_readlane(bpos, __builtin_ctzll(mask));
        } else {
            // exact tie fallback: u64 (value, pos) butterfly min
            unsigned long long kk =
                ((unsigned long long)bmin << 32) | (unsigned)bpos;
#pragma unroll
            for (int m = 1; m < 64; m <<= 1) {
                unsigned long long o = __shfl_xor(kk, m, 64);
                kk = (o < kk) ? o : kk;
            }
            wp = (int)(kk & 0xFFFFFFFFull);
        }
        if (l == 63) { wvals[w] = wmin; wposs[w] = wp; }
        __syncthreads();                 // A: wave candidates visible
        unsigned v0 = wvals[0], v1 = wvals[1];
        int q0 = wposs[0], q1 = wposs[1];
        bool take1 = (v1 < v0) || (v1 == v0 && q1 < q0);
        unsigned kv = take1 ? v1 : v0;
        int kp = take1 ? q1 : q0;
        if (k == 0) pos0 = kp;
        if (t == k) { resv = kv; resp = kp; }
        int own = kp & 127;
        if (t == own) dk[SKN(kp)] = 0xFFFFFFFFu;   // invalidate popped slot
        __syncthreads();                 // B: invalidation visible
        // wave 0 rescans owner's column (64 entries, one per lane)
        if (w == 0) {
            int p = l * 128 + own;       // monotone in l
            unsigned vv = dk[SKN(p)];
            unsigned cmin = wave_minu(vv);
            unsigned long long m2 = __ballot(vv == cmin);
            // lowest matching lane == lowest p (monotone) -> exact
            int cp = __builtin_amdgcn_readlane(p, __builtin_ctzll(m2));
            if (l == 63) { colv = cmin; colp = cp; }
        }
        __syncthreads();                 // C: rescan result visible
        if (t == own) { bmin = colv; bpos = colp; }
        // owner's read of colv/colp is separated from the next write by
        // barriers A and B of the next iteration.
    }
    if (t < GG) {
        gidx[(long)Q * GG + t] = (resv > SORT_R2) ? pos0 : resp;
    }
}

// ---------------------------------------------------------------------------
// Kernel 5: gather + 1x1 conv (W: 128x67) + relu + max over group.
// Block = 256 thr = 4 waves = 4 queries; W rows live in registers.
// ---------------------------------------------------------------------------
__global__ __launch_bounds__(256, 2) void k_mlp(const float4* __restrict__ pts4,
                                                const float* __restrict__ feaT,
                                                const float4* __restrict__ qpts,
                                                const int* __restrict__ gidx,
                                                const float* __restrict__ W,
                                                float* __restrict__ out) {
    __shared__ float sm[8704];   // max(8576 W floats, 4*32*68 grouped floats)
    int t = threadIdx.x, l = t & 63, w = t >> 6;

    for (int i = t; i < 8576; i += 256) sm[i] = W[i];
    __syncthreads();
    float wa[68], wb[68];
#pragma unroll
    for (int c = 0; c < 68; c++) {
        wa[c] = (c < 67) ? sm[l * 67 + c] : 0.f;
        wb[c] = (c < 67) ? sm[(l + 64) * 67 + c] : 0.f;
    }
    __syncthreads();   // done reading W region before reuse

    int Q = blockIdx.x * 4 + w;
    int b = Q >> 10, s = Q & 1023;
    float4 q = qpts[Q];
    const int* gi = gidx + (long)Q * GG;
    int base = w * 2176;   // 32*68 per wave

    if (l < 32) {
        int idx = gi[l];
        float4 p = pts4[(long)b * NN + idx];
        float4 rc = make_float4(__fsub_rn(p.x, q.x), __fsub_rn(p.y, q.y),
                                __fsub_rn(p.z, q.z), 0.f);
        *(float4*)&sm[base + l * 68 + 64] = rc;
    }
    {
        int g = l >> 1, half = l & 1;
        int idx = gi[g];
        const float4* f4 = (const float4*)(feaT + ((long)b * NN + idx) * 64);
#pragma unroll
        for (int k = 0; k < 8; k++) {
            *(float4*)&sm[base + g * 68 + half * 32 + k * 4] = f4[half * 8 + k];
        }
    }
    __syncthreads();

    float m0 = -1e30f, m1 = -1e30f;
#pragma unroll 2
    for (int g = 0; g < GG; g++) {
        float a0 = 0.f, a1 = 0.f;
#pragma unroll
        for (int c4 = 0; c4 < 17; c4++) {
            float4 gv = *(float4*)&sm[base + g * 68 + c4 * 4];
            a0 = fmaf(gv.x, wa[4 * c4 + 0], a0);
            a0 = fmaf(gv.y, wa[4 * c4 + 1], a0);
            a0 = fmaf(gv.z, wa[4 * c4 + 2], a0);
            a0 = fmaf(gv.w, wa[4 * c4 + 3], a0);
            a1 = fmaf(gv.x, wb[4 * c4 + 0], a1);
            a1 = fmaf(gv.y, wb[4 * c4 + 1], a1);
            a1 = fmaf(gv.z, wb[4 * c4 + 2], a1);
            a1 = fmaf(gv.w, wb[4 * c4 + 3], a1);
        }
        m0 = fmaxf(m0, a0);
        m1 = fmaxf(m1, a1);
    }
    // outputs: (B,3,S) then (B,128,S); relu(max) == max(relu)
    out[49152 + ((long)b * 128 + l) * SS + s]      = fmaxf(m0, 0.f);
    out[49152 + ((long)b * 128 + l + 64) * SS + s] = fmaxf(m1, 0.f);
}

// ---------------------------------------------------------------------------
extern "C" void kernel_launch(void* const* d_in, const int* in_sizes, int n_in,
                              void* d_out, int out_size, void* d_ws, size_t ws_size,
                              hipStream_t stream) {
    const float* coor = (const float*)d_in[0];   // (16,3,8192)
    const float* fea  = (const float*)d_in[1];   // (16,64,8192)
    const float* Wm   = (const float*)d_in[2];   // (128,67)
    float* out = (float*)d_out;

    char* ws = (char*)d_ws;
    float4* pts4 = (float4*)ws;                               //  2 MB
    float*  feaT = (float*)(ws + 2097152);                    // 32 MB
    float4* qpts = (float4*)(ws + 2097152 + 33554432);        // 256 KB
    int*    gidx = (int*)(ws + 2097152 + 33554432 + 262144);  //  2 MB

    k_pts<<<(BB * NN) / 256, 256, 0, stream>>>(coor, pts4);
    k_tr<<<dim3(NN / 64, BB), 256, 0, stream>>>(fea, feaT);
    k_fps<<<BB, 1024, 0, stream>>>(pts4, qpts, out);
    k_knn<<<BB * SS, 128, 0, stream>>>(pts4, qpts, gidx);
    k_mlp<<<(BB * SS) / 4, 256, 0, stream>>>(pts4, feaT, qpts, gidx, Wm, out);
}

// Round 9
// 1500.957 us; speedup vs baseline: 1.0700x; 1.0700x over previous
//
#include <hip/hip_runtime.h>
#include <hip/hip_bf16.h>

// Problem constants
#define BB 16
#define NN 8192
#define SS 1024
#define GG 32
// sortable(1.0f) = 0x3F800000 ^ 0x80000000
#define SORT_R2 0xBF800000u

typedef float v2f __attribute__((ext_vector_type(2)));

__device__ __forceinline__ unsigned sortable(float f) {
    unsigned u = __float_as_uint(f);
    return u ^ ((unsigned)(((int)u) >> 31) | 0x80000000u);
}

// f32 max-combine with a DPP-permuted copy (2 slots: v_mov_dpp + v_max_f32).
// row_shr:n = 0x110|n, row_bcast15 = 0x142, row_bcast31 = 0x143.
template <int CTRL, int RM>
__device__ __forceinline__ float dpp_maxf(float v) {
    int i = __float_as_int(v);
    int p = __builtin_amdgcn_update_dpp(i, i, CTRL, RM, 0xF, false);
    return fmaxf(v, __int_as_float(p));
}

// u32 min-combine with a DPP-permuted copy (2 slots).
template <int CTRL, int RM>
__device__ __forceinline__ unsigned dpp_minu(unsigned v) {
    int p = __builtin_amdgcn_update_dpp((int)v, (int)v, CTRL, RM, 0xF, false);
    return min(v, (unsigned)p);
}

__device__ __forceinline__ float fmax3(float a, float b, float c) {
    return fmaxf(fmaxf(a, b), c);   // fuses to v_max3_f32
}

// ---------------------------------------------------------------------------
// Kernel 1: pack pts4[b][n] = {x, y, z, (x*x+y*y)+z*z}  (rn ops, no contraction)
// ---------------------------------------------------------------------------
__global__ __launch_bounds__(256) void k_pts(const float* __restrict__ coor,
                                             float4* __restrict__ pts4) {
    int i = blockIdx.x * 256 + threadIdx.x;   // 0 .. B*N-1
    int b = i >> 13, n = i & (NN - 1);
    const float* cb = coor + (long)b * 3 * NN;
    float x = cb[n], y = cb[NN + n], z = cb[2 * NN + n];
    float pn = __fadd_rn(__fadd_rn(__fmul_rn(x, x), __fmul_rn(y, y)), __fmul_rn(z, z));
    pts4[i] = make_float4(x, y, z, pn);
}

// ---------------------------------------------------------------------------
// Kernel 2: transpose fea (B,64,N) -> feaT (B,N,64)
// ---------------------------------------------------------------------------
__global__ __launch_bounds__(256) void k_tr(const float* __restrict__ fea,
                                            float* __restrict__ feaT) {
    __shared__ float tile[64][65];
    int b = blockIdx.y, n0 = blockIdx.x * 64;
    int t = threadIdx.x;
    int nl = t & 63, cb = t >> 6;
#pragma unroll
    for (int i = 0; i < 16; i++) {
        int c = cb * 16 + i;
        tile[nl][c] = fea[((long)b * 64 + c) * NN + n0 + nl];
    }
    __syncthreads();
    int cl = t & 63, nb = t >> 6;
#pragma unroll
    for (int i = 0; i < 16; i++) {
        int n = nb * 16 + i;
        feaT[((long)b * NN + n0 + n) * 64 + cl] = tile[n][cl];
    }
}

// ---------------------------------------------------------------------------
// Kernel 3: farthest point sampling. One block (512 thr) per batch.
// v9 == v5 verbatim (the measured optimum: 926 us). 256-thr (R7) and
// 1024-thr (R8) variants both landed ~1010 us -> 512 thr / 2 waves/SIMD is
// the sweet spot of this two-barrier value-first structure. Packed v2f
// distance update, contract(off): bit-exact rn ops; value-only f32 DPP wave
// max; rare block-global winner path via equality scan + LDS atomicMin
// (exact lowest-flat-index ties).
// ---------------------------------------------------------------------------
__global__ __launch_bounds__(512) void k_fps(const float4* __restrict__ pts4,
                                             float4* __restrict__ qpts,
                                             float* __restrict__ out) {
#pragma clang fp contract(off)
    __shared__ float xs[NN], ys[NN], zs[NN];
    __shared__ int scur[SS];
    __shared__ __align__(16) float redv[2][8];
    __shared__ int sidx[2];
    int b = blockIdx.x;
    int t = threadIdx.x;
    const float4* P = pts4 + (long)b * NN;

    // pair j, half h -> point p = t + (2j+h)*512
    v2f px[8], py[8], pz[8], dist[8];
#pragma unroll
    for (int j = 0; j < 8; j++) {
        int p0 = t + (2 * j) * 512;
        int p1 = t + (2 * j + 1) * 512;
        float4 a = P[p0];
        float4 c = P[p1];
        px[j] = v2f{a.x, c.x};
        py[j] = v2f{a.y, c.y};
        pz[j] = v2f{a.z, c.z};
        dist[j] = v2f{1e10f, 1e10f};
        xs[p0] = a.x; ys[p0] = a.y; zs[p0] = a.z;
        xs[p1] = c.x; ys[p1] = c.y; zs[p1] = c.z;
    }
    if (t == 0) { sidx[0] = 0x7FFFFFFF; sidx[1] = 0x7FFFFFFF; }
    __syncthreads();

    int cur = 0;
    for (int s = 0; s < SS; s++) {
        int par = s & 1;
        float cx = xs[cur], cy = ys[cur], cz = zs[cur];
        if (t == 0) scur[s] = cur;
        v2f cx2 = v2f{cx, cx}, cy2 = v2f{cy, cy}, cz2 = v2f{cz, cz};
#pragma unroll
        for (int j = 0; j < 8; j++) {
            v2f dx = px[j] - cx2;
            v2f dy = py[j] - cy2;
            v2f dz = pz[j] - cz2;
            v2f xx = dx * dx;
            v2f yy = dy * dy;
            v2f zz = dz * dz;
            v2f sm = xx + yy;
            v2f d = sm + zz;
            dist[j] = __builtin_elementwise_min(dist[j], d);
        }
        // value-only per-thread max: packed tree (7 pk-max) + final scalar
        v2f m01 = __builtin_elementwise_max(dist[0], dist[1]);
        v2f m23 = __builtin_elementwise_max(dist[2], dist[3]);
        v2f m45 = __builtin_elementwise_max(dist[4], dist[5]);
        v2f m67 = __builtin_elementwise_max(dist[6], dist[7]);
        v2f m03 = __builtin_elementwise_max(m01, m23);
        v2f m47 = __builtin_elementwise_max(m45, m67);
        v2f m07 = __builtin_elementwise_max(m03, m47);
        float bv = fmaxf(m07.x, m07.y);
        // 64-lane DPP f32 max; full-wave max lands in lane 63
        float wv = bv;
        wv = dpp_maxf<0x111, 0xF>(wv);   // row_shr:1
        wv = dpp_maxf<0x112, 0xF>(wv);   // row_shr:2
        wv = dpp_maxf<0x114, 0xF>(wv);   // row_shr:4
        wv = dpp_maxf<0x118, 0xF>(wv);   // row_shr:8
        wv = dpp_maxf<0x142, 0xA>(wv);   // row_bcast:15 (rows 1,3)
        wv = dpp_maxf<0x143, 0xC>(wv);   // row_bcast:31 (rows 2,3)
        if ((t & 63) == 63) redv[par][t >> 6] = wv;
        __syncthreads();                 // barrier 1
        float4 r0 = *(const float4*)redv[par];
        float4 r1 = *(const float4*)(redv[par] + 4);
        float gmax = fmaxf(fmax3(r0.x, r0.y, r0.z),
                           fmax3(r0.w, fmax3(r1.x, r1.y, r1.z), r1.w));
        // reset the OTHER sidx slot (used at s+1); barrier 2 separates it
        // from s+1's atomics.
        if (t == 0) sidx[1 - par] = 0x7FFFFFFF;
        if (bv == gmax) {
            // block-rare path (usually 1 thread): lowest matching ord
            int jj = 16;
#pragma unroll
            for (int j = 7; j >= 0; j--) {
                jj = (dist[j].y == gmax) ? (2 * j + 1) : jj;
                jj = (dist[j].x == gmax) ? (2 * j) : jj;
            }
            atomicMin(&sidx[par], t + jj * 512);
        }
        __syncthreads();                 // barrier 2
        cur = sidx[par];
    }
    __syncthreads();

    // epilogue: write new_coor (B,3,S) and query points from recorded indices
#pragma unroll
    for (int s = t; s < SS; s += 512) {
        int c = scur[s];
        float cx = xs[c], cy = ys[c], cz = zs[c];
        out[(long)b * 3 * SS + s]          = cx;
        out[(long)b * 3 * SS + SS + s]     = cy;
        out[(long)b * 3 * SS + 2 * SS + s] = cz;
        float qn = __fadd_rn(__fadd_rn(__fmul_rn(cx, cx), __fmul_rn(cy, cy)),
                             __fmul_rn(cz, cz));
        qpts[(long)b * SS + s] = make_float4(cx, cy, cz, qn);
    }
}

// ---------------------------------------------------------------------------
// Kernel 4 (FUSED knn+mlp): one 64-thr block per query.
// Phase 1: exact 32-NN scan (R6-v2, unroll 8 for deeper L2 pipelining).
// Phase 2: W -> 134 VGPRs (L2-hot loads issued before pops; latency hides
//          under the pop loop).
// Phase 3: 32 pops (R6-v2 verbatim: u32 DPP min + ballot fast path, exact
//          u64 butterfly on ties).
// Phase 4: gather fea+relcoor into the DEAD dk LDS region (grouped tile).
// Phase 5: 1x1 conv + relu + max-pool, store straight to out. No gidx.
// LDS stays ~34 KB -> 4 blocks/CU residency preserved.
// ---------------------------------------------------------------------------
#define SKEW(p) ((p) + ((p) >> 5))
__global__ __launch_bounds__(64) void k_knn_mlp(const float4* __restrict__ pts4,
                                                const float* __restrict__ feaT,
                                                const float4* __restrict__ qpts,
                                                const float* __restrict__ W,
                                                float* __restrict__ out) {
    __shared__ __align__(16) unsigned dk[NN + NN / 32];   // 33792 B
    __shared__ int sidxs[GG];
    float* grouped = (float*)dk;   // reused after pops: 32*68 floats (8704 B)

    int Q = blockIdx.x;                      // b*1024 + s
    int b = Q >> 10, s = Q & 1023;
    int l = threadIdx.x;
    float4 q = qpts[Q];
    const float4* P = pts4 + (long)b * NN;

    // ---- Phase 1: distance scan ----
    unsigned bmin = 0xFFFFFFFFu;
    int bpos = 0;
#pragma unroll 8
    for (int j = 0; j < 128; j++) {
        int p = j * 64 + l;
        float4 v = P[p];
        float dot = __fadd_rn(__fadd_rn(__fmul_rn(q.x, v.x), __fmul_rn(q.y, v.y)),
                              __fmul_rn(q.z, v.z));
        float d = __fadd_rn(__fsub_rn(q.w, __fmul_rn(2.0f, dot)), v.w);
        unsigned u = sortable(d);
        dk[SKEW(p)] = u;
        if (u < bmin) { bmin = u; bpos = p; }   // ascending p -> earliest index on tie
    }
    __syncthreads();

    // ---- Phase 2: W rows into registers (latency overlaps the pop loop) ----
    float wa[68], wb[68];
    {
        const float* Wr = W + l * 67;
#pragma unroll
        for (int c = 0; c < 67; c++) {
            wa[c] = Wr[c];
            wb[c] = Wr[64 * 67 + c];
        }
        wa[67] = 0.f; wb[67] = 0.f;
    }

    // ---- Phase 3: 32 pops ----
    unsigned resv = 0;
    int resp = 0, pos0 = 0;
    for (int k = 0; k < GG; k++) {
        unsigned mv = bmin;
        mv = dpp_minu<0x111, 0xF>(mv);
        mv = dpp_minu<0x112, 0xF>(mv);
        mv = dpp_minu<0x114, 0xF>(mv);
        mv = dpp_minu<0x118, 0xF>(mv);
        mv = dpp_minu<0x142, 0xA>(mv);
        mv = dpp_minu<0x143, 0xC>(mv);
        unsigned wmin = (unsigned)__builtin_amdgcn_readlane((int)mv, 63);
        unsigned long long mask = __ballot(bmin == wmin);
        int wpos;
        if (__builtin_popcountll(mask) == 1) {
            int owner = __builtin_ctzll(mask);
            wpos = __builtin_amdgcn_readlane(bpos, owner);
        } else {
            unsigned long long kk =
                ((unsigned long long)bmin << 32) | (unsigned)bpos;
#pragma unroll
            for (int m = 1; m < 64; m <<= 1) {
                unsigned long long o = __shfl_xor(kk, m, 64);
                kk = (o < kk) ? o : kk;
            }
            wpos = (int)(kk & 0xFFFFFFFFull);
        }
        if (k == 0) pos0 = wpos;
        if (l == k) { resv = wmin; resp = wpos; }
        int own = wpos & 63;
        if (l == own) dk[SKEW(wpos)] = 0xFFFFFFFFu;   // invalidate popped slot
        __syncthreads();
        // cooperative rescan of owner's column (its 128 points)
        int p1 = l * 64 + own;
        int p2 = (l + 64) * 64 + own;
        unsigned v1 = dk[SKEW(p1)], v2 = dk[SKEW(p2)];
        bool c = v2 < v1;                 // p1 < p2, so tie keeps earliest
        unsigned cv = c ? v2 : v1;
        int cp = c ? p2 : p1;
        unsigned cm = cv;
        cm = dpp_minu<0x111, 0xF>(cm);
        cm = dpp_minu<0x112, 0xF>(cm);
        cm = dpp_minu<0x114, 0xF>(cm);
        cm = dpp_minu<0x118, 0xF>(cm);
        cm = dpp_minu<0x142, 0xA>(cm);
        cm = dpp_minu<0x143, 0xC>(cm);
        unsigned colmin = (unsigned)__builtin_amdgcn_readlane((int)cm, 63);
        unsigned long long m2 = __ballot(cv == colmin);
        int colpos;
        if (__builtin_popcountll(m2) == 1) {
            colpos = __builtin_amdgcn_readlane(cp, __builtin_ctzll(m2));
        } else {
            unsigned long long kk =
                ((unsigned long long)cv << 32) | (unsigned)cp;
#pragma unroll
            for (int m = 1; m < 64; m <<= 1) {
                unsigned long long o = __shfl_xor(kk, m, 64);
                kk = (o < kk) ? o : kk;
            }
            colpos = (int)(kk & 0xFFFFFFFFull);
        }
        if (l == own) { bmin = colmin; bpos = colpos; }
        __syncthreads();
    }

    // ---- Phase 4: final indices + gather into reused LDS ----
    if (l < GG) sidxs[l] = (resv > SORT_R2) ? pos0 : resp;   // radius filter
    __syncthreads();   // sidxs visible; dk dead from here on

    if (l < 32) {
        int idx = sidxs[l];
        float4 p = pts4[(long)b * NN + idx];
        float4 rc = make_float4(__fsub_rn(p.x, q.x), __fsub_rn(p.y, q.y),
                                __fsub_rn(p.z, q.z), 0.f);
        *(float4*)&grouped[l * 68 + 64] = rc;
    }
    {
        int g = l >> 1, half = l & 1;
        int idx = sidxs[g];
        const float4* f4 = (const float4*)(feaT + ((long)b * NN + idx) * 64);
#pragma unroll
        for (int k4 = 0; k4 < 8; k4++) {
            *(float4*)&grouped[g * 68 + half * 32 + k4 * 4] = f4[half * 8 + k4];
        }
    }
    __syncthreads();

    // ---- Phase 5: 1x1 conv + relu + max over group ----
    float m0 = -1e30f, m1 = -1e30f;
#pragma unroll 2
    for (int g = 0; g < GG; g++) {
        float a0 = 0.f, a1 = 0.f;
#pragma unroll
        for (int c4 = 0; c4 < 17; c4++) {
            float4 gv = *(float4*)&grouped[g * 68 + c4 * 4];
            a0 = fmaf(gv.x, wa[4 * c4 + 0], a0);
            a0 = fmaf(gv.y, wa[4 * c4 + 1], a0);
            a0 = fmaf(gv.z, wa[4 * c4 + 2], a0);
            a0 = fmaf(gv.w, wa[4 * c4 + 3], a0);
            a1 = fmaf(gv.x, wb[4 * c4 + 0], a1);
            a1 = fmaf(gv.y, wb[4 * c4 + 1], a1);
            a1 = fmaf(gv.z, wb[4 * c4 + 2], a1);
            a1 = fmaf(gv.w, wb[4 * c4 + 3], a1);
        }
        m0 = fmaxf(m0, a0);
        m1 = fmaxf(m1, a1);
    }
    // outputs: (B,3,S) then (B,128,S); relu(max) == max(relu)
    out[49152 + ((long)b * 128 + l) * SS + s]      = fmaxf(m0, 0.f);
    out[49152 + ((long)b * 128 + l + 64) * SS + s] = fmaxf(m1, 0.f);
}

// ---------------------------------------------------------------------------
extern "C" void kernel_launch(void* const* d_in, const int* in_sizes, int n_in,
                              void* d_out, int out_size, void* d_ws, size_t ws_size,
                              hipStream_t stream) {
    const float* coor = (const float*)d_in[0];   // (16,3,8192)
    const float* fea  = (const float*)d_in[1];   // (16,64,8192)
    const float* Wm   = (const float*)d_in[2];   // (128,67)
    float* out = (float*)d_out;

    char* ws = (char*)d_ws;
    float4* pts4 = (float4*)ws;                               //  2 MB
    float*  feaT = (float*)(ws + 2097152);                    // 32 MB
    float4* qpts = (float4*)(ws + 2097152 + 33554432);        // 256 KB

    k_pts<<<(BB * NN) / 256, 256, 0, stream>>>(coor, pts4);
    k_tr<<<dim3(NN / 64, BB), 256, 0, stream>>>(fea, feaT);
    k_fps<<<BB, 512, 0, stream>>>(pts4, qpts, out);
    k_knn_mlp<<<BB * SS, 64, 0, stream>>>(pts4, feaT, qpts, Wm, out);
}

// Round 12
// 1489.063 us; speedup vs baseline: 1.0785x; 1.0080x over previous
//
#include <hip/hip_runtime.h>
#include <hip/hip_bf16.h>

// Problem constants
#define BB 16
#define NN 8192
#define SS 1024
#define GG 32
// sortable(1.0f) = 0x3F800000 ^ 0x80000000
#define SORT_R2 0xBF800000u

typedef float v2f __attribute__((ext_vector_type(2)));

__device__ __forceinline__ unsigned sortable(float f) {
    unsigned u = __float_as_uint(f);
    return u ^ ((unsigned)(((int)u) >> 31) | 0x80000000u);
}

// f32 max-combine with a DPP-permuted copy (2 slots: v_mov_dpp + v_max_f32).
// row_shr:n = 0x110|n, row_bcast15 = 0x142, row_bcast31 = 0x143.
template <int CTRL, int RM>
__device__ __forceinline__ float dpp_maxf(float v) {
    int i = __float_as_int(v);
    int p = __builtin_amdgcn_update_dpp(i, i, CTRL, RM, 0xF, false);
    return fmaxf(v, __int_as_float(p));
}

// u32 min-combine with a DPP-permuted copy (2 slots).
template <int CTRL, int RM>
__device__ __forceinline__ unsigned dpp_minu(unsigned v) {
    int p = __builtin_amdgcn_update_dpp((int)v, (int)v, CTRL, RM, 0xF, false);
    return min(v, (unsigned)p);
}

__device__ __forceinline__ float fmax3(float a, float b, float c) {
    return fmaxf(fmaxf(a, b), c);   // fuses to v_max3_f32
}

// ---------------------------------------------------------------------------
// Kernel 1: pack pts4[b][n] = {x, y, z, (x*x+y*y)+z*z}  (rn ops, no contraction)
// ---------------------------------------------------------------------------
__global__ __launch_bounds__(256) void k_pts(const float* __restrict__ coor,
                                             float4* __restrict__ pts4) {
    int i = blockIdx.x * 256 + threadIdx.x;   // 0 .. B*N-1
    int b = i >> 13, n = i & (NN - 1);
    const float* cb = coor + (long)b * 3 * NN;
    float x = cb[n], y = cb[NN + n], z = cb[2 * NN + n];
    float pn = __fadd_rn(__fadd_rn(__fmul_rn(x, x), __fmul_rn(y, y)), __fmul_rn(z, z));
    pts4[i] = make_float4(x, y, z, pn);
}

// ---------------------------------------------------------------------------
// Kernel 2: transpose fea (B,64,N) -> feaT (B,N,64)
// ---------------------------------------------------------------------------
__global__ __launch_bounds__(256) void k_tr(const float* __restrict__ fea,
                                            float* __restrict__ feaT) {
    __shared__ float tile[64][65];
    int b = blockIdx.y, n0 = blockIdx.x * 64;
    int t = threadIdx.x;
    int nl = t & 63, cb = t >> 6;
#pragma unroll
    for (int i = 0; i < 16; i++) {
        int c = cb * 16 + i;
        tile[nl][c] = fea[((long)b * 64 + c) * NN + n0 + nl];
    }
    __syncthreads();
    int cl = t & 63, nb = t >> 6;
#pragma unroll
    for (int i = 0; i < 16; i++) {
        int n = nb * 16 + i;
        feaT[((long)b * NN + n0 + n) * 64 + cl] = tile[n][cl];
    }
}

// ---------------------------------------------------------------------------
// Kernel 3: farthest point sampling. One block (512 thr) per batch.
// v9 (== v5, the measured optimum ~930 us). Packed v2f distance update,
// contract(off): bit-exact rn ops; value-only f32 DPP wave max; rare
// block-global winner path via equality scan + LDS atomicMin.
// ---------------------------------------------------------------------------
__global__ __launch_bounds__(512) void k_fps(const float4* __restrict__ pts4,
                                             float4* __restrict__ qpts,
                                             float* __restrict__ out) {
#pragma clang fp contract(off)
    __shared__ float xs[NN], ys[NN], zs[NN];
    __shared__ int scur[SS];
    __shared__ __align__(16) float redv[2][8];
    __shared__ int sidx[2];
    int b = blockIdx.x;
    int t = threadIdx.x;
    const float4* P = pts4 + (long)b * NN;

    // pair j, half h -> point p = t + (2j+h)*512
    v2f px[8], py[8], pz[8], dist[8];
#pragma unroll
    for (int j = 0; j < 8; j++) {
        int p0 = t + (2 * j) * 512;
        int p1 = t + (2 * j + 1) * 512;
        float4 a = P[p0];
        float4 c = P[p1];
        px[j] = v2f{a.x, c.x};
        py[j] = v2f{a.y, c.y};
        pz[j] = v2f{a.z, c.z};
        dist[j] = v2f{1e10f, 1e10f};
        xs[p0] = a.x; ys[p0] = a.y; zs[p0] = a.z;
        xs[p1] = c.x; ys[p1] = c.y; zs[p1] = c.z;
    }
    if (t == 0) { sidx[0] = 0x7FFFFFFF; sidx[1] = 0x7FFFFFFF; }
    __syncthreads();

    int cur = 0;
    for (int s = 0; s < SS; s++) {
        int par = s & 1;
        float cx = xs[cur], cy = ys[cur], cz = zs[cur];
        if (t == 0) scur[s] = cur;
        v2f cx2 = v2f{cx, cx}, cy2 = v2f{cy, cy}, cz2 = v2f{cz, cz};
#pragma unroll
        for (int j = 0; j < 8; j++) {
            v2f dx = px[j] - cx2;
            v2f dy = py[j] - cy2;
            v2f dz = pz[j] - cz2;
            v2f xx = dx * dx;
            v2f yy = dy * dy;
            v2f zz = dz * dz;
            v2f sm = xx + yy;
            v2f d = sm + zz;
            dist[j] = __builtin_elementwise_min(dist[j], d);
        }
        // value-only per-thread max: packed tree (7 pk-max) + final scalar
        v2f m01 = __builtin_elementwise_max(dist[0], dist[1]);
        v2f m23 = __builtin_elementwise_max(dist[2], dist[3]);
        v2f m45 = __builtin_elementwise_max(dist[4], dist[5]);
        v2f m67 = __builtin_elementwise_max(dist[6], dist[7]);
        v2f m03 = __builtin_elementwise_max(m01, m23);
        v2f m47 = __builtin_elementwise_max(m45, m67);
        v2f m07 = __builtin_elementwise_max(m03, m47);
        float bv = fmaxf(m07.x, m07.y);
        // 64-lane DPP f32 max; full-wave max lands in lane 63
        float wv = bv;
        wv = dpp_maxf<0x111, 0xF>(wv);   // row_shr:1
        wv = dpp_maxf<0x112, 0xF>(wv);   // row_shr:2
        wv = dpp_maxf<0x114, 0xF>(wv);   // row_shr:4
        wv = dpp_maxf<0x118, 0xF>(wv);   // row_shr:8
        wv = dpp_maxf<0x142, 0xA>(wv);   // row_bcast:15 (rows 1,3)
        wv = dpp_maxf<0x143, 0xC>(wv);   // row_bcast:31 (rows 2,3)
        if ((t & 63) == 63) redv[par][t >> 6] = wv;
        __syncthreads();                 // barrier 1
        float4 r0 = *(const float4*)redv[par];
        float4 r1 = *(const float4*)(redv[par] + 4);
        float gmax = fmaxf(fmax3(r0.x, r0.y, r0.z),
                           fmax3(r0.w, fmax3(r1.x, r1.y, r1.z), r1.w));
        // reset the OTHER sidx slot (used at s+1); barrier 2 separates it
        // from s+1's atomics.
        if (t == 0) sidx[1 - par] = 0x7FFFFFFF;
        if (bv == gmax) {
            // block-rare path (usually 1 thread): lowest matching ord
            int jj = 16;
#pragma unroll
            for (int j = 7; j >= 0; j--) {
                jj = (dist[j].y == gmax) ? (2 * j + 1) : jj;
                jj = (dist[j].x == gmax) ? (2 * j) : jj;
            }
            atomicMin(&sidx[par], t + jj * 512);
        }
        __syncthreads();                 // barrier 2
        cur = sidx[par];
    }
    __syncthreads();

    // epilogue: write new_coor (B,3,S) and query points from recorded indices
#pragma unroll
    for (int s = t; s < SS; s += 512) {
        int c = scur[s];
        float cx = xs[c], cy = ys[c], cz = zs[c];
        out[(long)b * 3 * SS + s]          = cx;
        out[(long)b * 3 * SS + SS + s]     = cy;
        out[(long)b * 3 * SS + 2 * SS + s] = cz;
        float qn = __fadd_rn(__fadd_rn(__fmul_rn(cx, cx), __fmul_rn(cy, cy)),
                             __fmul_rn(cz, cz));
        qpts[(long)b * SS + s] = make_float4(cx, cy, cz, qn);
    }
}

// ---------------------------------------------------------------------------
// Kernel 4 (FUSED knn+mlp): one 64-thr block per query — R9 code verbatim
// (passed, absmax 0.0), with two zero-semantic-risk changes:
//   * __launch_bounds__(64, 1): dk LDS caps residency at 4 blocks/CU anyway,
//     so lift the register cap — R9's VGPR_Count=132 < 136 W regs proves W
//     was spilling to scratch and reloading inside the MLP loop.
//   * scan unroll 8 -> 16: more loads in flight for the L2-latency-bound
//     scan at 1 wave/SIMD.
// The dk-free redesigns (R10/R11) both failed with identical absmax and are
// shelved pending offline A/B.
// ---------------------------------------------------------------------------
#define SKEW(p) ((p) + ((p) >> 5))
__global__ __launch_bounds__(64, 1) void k_knn_mlp(const float4* __restrict__ pts4,
                                                   const float* __restrict__ feaT,
                                                   const float4* __restrict__ qpts,
                                                   const float* __restrict__ W,
                                                   float* __restrict__ out) {
    __shared__ __align__(16) unsigned dk[NN + NN / 32];   // 33792 B
    __shared__ int sidxs[GG];
    float* grouped = (float*)dk;   // reused after pops: 32*68 floats (8704 B)

    int Q = blockIdx.x;                      // b*1024 + s
    int b = Q >> 10, s = Q & 1023;
    int l = threadIdx.x;
    float4 q = qpts[Q];
    const float4* P = pts4 + (long)b * NN;

    // ---- Phase 1: distance scan ----
    unsigned bmin = 0xFFFFFFFFu;
    int bpos = 0;
#pragma unroll 16
    for (int j = 0; j < 128; j++) {
        int p = j * 64 + l;
        float4 v = P[p];
        float dot = __fadd_rn(__fadd_rn(__fmul_rn(q.x, v.x), __fmul_rn(q.y, v.y)),
                              __fmul_rn(q.z, v.z));
        float d = __fadd_rn(__fsub_rn(q.w, __fmul_rn(2.0f, dot)), v.w);
        unsigned u = sortable(d);
        dk[SKEW(p)] = u;
        if (u < bmin) { bmin = u; bpos = p; }   // ascending p -> earliest index on tie
    }
    __syncthreads();

    // ---- Phase 2: W rows into registers (latency overlaps the pop loop) ----
    float wa[68], wb[68];
    {
        const float* Wr = W + l * 67;
#pragma unroll
        for (int c = 0; c < 67; c++) {
            wa[c] = Wr[c];
            wb[c] = Wr[64 * 67 + c];
        }
        wa[67] = 0.f; wb[67] = 0.f;
    }

    // ---- Phase 3: 32 pops ----
    unsigned resv = 0;
    int resp = 0, pos0 = 0;
    for (int k = 0; k < GG; k++) {
        unsigned mv = bmin;
        mv = dpp_minu<0x111, 0xF>(mv);
        mv = dpp_minu<0x112, 0xF>(mv);
        mv = dpp_minu<0x114, 0xF>(mv);
        mv = dpp_minu<0x118, 0xF>(mv);
        mv = dpp_minu<0x142, 0xA>(mv);
        mv = dpp_minu<0x143, 0xC>(mv);
        unsigned wmin = (unsigned)__builtin_amdgcn_readlane((int)mv, 63);
        unsigned long long mask = __ballot(bmin == wmin);
        int wpos;
        if (__builtin_popcountll(mask) == 1) {
            int owner = __builtin_ctzll(mask);
            wpos = __builtin_amdgcn_readlane(bpos, owner);
        } else {
            unsigned long long kk =
                ((unsigned long long)bmin << 32) | (unsigned)bpos;
#pragma unroll
            for (int m = 1; m < 64; m <<= 1) {
                unsigned long long o = __shfl_xor(kk, m, 64);
                kk = (o < kk) ? o : kk;
            }
            wpos = (int)(kk & 0xFFFFFFFFull);
        }
        if (k == 0) pos0 = wpos;
        if (l == k) { resv = wmin; resp = wpos; }
        int own = wpos & 63;
        if (l == own) dk[SKEW(wpos)] = 0xFFFFFFFFu;   // invalidate popped slot
        __syncthreads();
        // cooperative rescan of owner's column (its 128 points)
        int p1 = l * 64 + own;
        int p2 = (l + 64) * 64 + own;
        unsigned v1 = dk[SKEW(p1)], v2 = dk[SKEW(p2)];
        bool c = v2 < v1;                 // p1 < p2, so tie keeps earliest
        unsigned cv = c ? v2 : v1;
        int cp = c ? p2 : p1;
        unsigned cm = cv;
        cm = dpp_minu<0x111, 0xF>(cm);
        cm = dpp_minu<0x112, 0xF>(cm);
        cm = dpp_minu<0x114, 0xF>(cm);
        cm = dpp_minu<0x118, 0xF>(cm);
        cm = dpp_minu<0x142, 0xA>(cm);
        cm = dpp_minu<0x143, 0xC>(cm);
        unsigned colmin = (unsigned)__builtin_amdgcn_readlane((int)cm, 63);
        unsigned long long m2 = __ballot(cv == colmin);
        int colpos;
        if (__builtin_popcountll(m2) == 1) {
            colpos = __builtin_amdgcn_readlane(cp, __builtin_ctzll(m2));
        } else {
            unsigned long long kk =
                ((unsigned long long)cv << 32) | (unsigned)cp;
#pragma unroll
            for (int m = 1; m < 64; m <<= 1) {
                unsigned long long o = __shfl_xor(kk, m, 64);
                kk = (o < kk) ? o : kk;
            }
            colpos = (int)(kk & 0xFFFFFFFFull);
        }
        if (l == own) { bmin = colmin; bpos = colpos; }
        __syncthreads();
    }

    // ---- Phase 4: final indices + gather into reused LDS ----
    if (l < GG) sidxs[l] = (resv > SORT_R2) ? pos0 : resp;   // radius filter
    __syncthreads();   // sidxs visible; dk dead from here on

    if (l < 32) {
        int idx = sidxs[l];
        float4 p = pts4[(long)b * NN + idx];
        float4 rc = make_float4(__fsub_rn(p.x, q.x), __fsub_rn(p.y, q.y),
                                __fsub_rn(p.z, q.z), 0.f);
        *(float4*)&grouped[l * 68 + 64] = rc;
    }
    {
        int g = l >> 1, half = l & 1;
        int idx = sidxs[g];
        const float4* f4 = (const float4*)(feaT + ((long)b * NN + idx) * 64);
#pragma unroll
        for (int k4 = 0; k4 < 8; k4++) {
            *(float4*)&grouped[g * 68 + half * 32 + k4 * 4] = f4[half * 8 + k4];
        }
    }
    __syncthreads();

    // ---- Phase 5: 1x1 conv + relu + max over group ----
    float m0 = -1e30f, m1 = -1e30f;
#pragma unroll 2
    for (int g = 0; g < GG; g++) {
        float a0 = 0.f, a1 = 0.f;
#pragma unroll
        for (int c4 = 0; c4 < 17; c4++) {
            float4 gv = *(float4*)&grouped[g * 68 + c4 * 4];
            a0 = fmaf(gv.x, wa[4 * c4 + 0], a0);
            a0 = fmaf(gv.y, wa[4 * c4 + 1], a0);
            a0 = fmaf(gv.z, wa[4 * c4 + 2], a0);
            a0 = fmaf(gv.w, wa[4 * c4 + 3], a0);
            a1 = fmaf(gv.x, wb[4 * c4 + 0], a1);
            a1 = fmaf(gv.y, wb[4 * c4 + 1], a1);
            a1 = fmaf(gv.z, wb[4 * c4 + 2], a1);
            a1 = fmaf(gv.w, wb[4 * c4 + 3], a1);
        }
        m0 = fmaxf(m0, a0);
        m1 = fmaxf(m1, a1);
    }
    // outputs: (B,3,S) then (B,128,S); relu(max) == max(relu)
    out[49152 + ((long)b * 128 + l) * SS + s]      = fmaxf(m0, 0.f);
    out[49152 + ((long)b * 128 + l + 64) * SS + s] = fmaxf(m1, 0.f);
}

// ---------------------------------------------------------------------------
extern "C" void kernel_launch(void* const* d_in, const int* in_sizes, int n_in,
                              void* d_out, int out_size, void* d_ws, size_t ws_size,
                              hipStream_t stream) {
    const float* coor = (const float*)d_in[0];   // (16,3,8192)
    const float* fea  = (const float*)d_in[1];   // (16,64,8192)
    const float* Wm   = (const float*)d_in[2];   // (128,67)
    float* out = (float*)d_out;

    char* ws = (char*)d_ws;
    float4* pts4 = (float4*)ws;                               //  2 MB
    float*  feaT = (float*)(ws + 2097152);                    // 32 MB
    float4* qpts = (float4*)(ws + 2097152 + 33554432);        // 256 KB

    k_pts<<<(BB * NN) / 256, 256, 0, stream>>>(coor, pts4);
    k_tr<<<dim3(NN / 64, BB), 256, 0, stream>>>(fea, feaT);
    k_fps<<<BB, 512, 0, stream>>>(pts4, qpts, out);
    k_knn_mlp<<<BB * SS, 64, 0, stream>>>(pts4, feaT, qpts, Wm, out);
}